// Round 13
// baseline (4637.991 us; speedup 1.0000x reference)
//
#include <hip/hip_runtime.h>
#include <stdint.h>

#define NB 64
#define NS 1024
#define ND 1024
#define NG 4096
#define CHUNK 128
#define NCHUNK 8
#define RING 32

typedef __attribute__((ext_vector_type(4))) float f32x4;
typedef __attribute__((ext_vector_type(8))) short bf16x8;

#define WAITV0 asm volatile("s_waitcnt vmcnt(0)" ::: "memory")

__device__ __forceinline__ float bf2f(uint16_t u) {
  return __uint_as_float(((uint32_t)u) << 16);
}
__device__ __forceinline__ uint16_t f2bf(float f) {
  uint32_t x = __float_as_uint(f);
  return (uint16_t)((x + 0x7fffu + ((x >> 16) & 1u)) >> 16);
}
__device__ __forceinline__ float sigmoidf_(float x) {
  return 1.f / (1.f + __expf(-x));
}
__device__ __forceinline__ float tanhf_(float x) {
  return 1.f - 2.f / (__expf(x + x) + 1.f);
}
__device__ __forceinline__ void gload_lds16(const void* g, void* l) {
  __builtin_amdgcn_global_load_lds(
      (const __attribute__((address_space(1))) uint32_t*)g,
      (__attribute__((address_space(3))) uint32_t*)l, 16, 0, 0);
}
// L1+L2-bypassing variant (cpol SC0|SC1): reads served from L3, where the
// producers' agent-scope stores are visible before their flag.
__device__ __forceinline__ void gload_lds16_nc(const void* g, void* l) {
  __builtin_amdgcn_global_load_lds(
      (const __attribute__((address_space(1))) uint32_t*)g,
      (__attribute__((address_space(3))) uint32_t*)l, 16, 0, 17);
}

// ---------------- convert fp32 -> bf16 ----------------
__global__ void k_cvt(const float* __restrict__ src, uint16_t* __restrict__ dst, int n4) {
  int stride = gridDim.x * blockDim.x;
  for (int i = blockIdx.x * blockDim.x + threadIdx.x; i < n4; i += stride) {
    float4 v = ((const float4*)src)[i];
    ushort4 o;
    o.x = f2bf(v.x); o.y = f2bf(v.y); o.z = f2bf(v.z); o.w = f2bf(v.w);
    ((ushort4*)dst)[i] = o;
  }
}

// ---------------- GEMM tile: [128 steps x 1024] x [1024 x 128] -> XP ----------------
__device__ __forceinline__ void gemm_tile(const uint16_t* __restrict__ A0,
                                          const uint16_t* __restrict__ Wx,
                                          uint16_t* __restrict__ XP,
                                          int b, int nb, int tid, char* lmem) {
  uint16_t* lAx = (uint16_t*)lmem;
  uint16_t* lBx = (uint16_t*)(lmem + 8192);
  const uint16_t* B0 = Wx + (size_t)(nb * 128) * ND;
  const int lane = tid & 63, wv = tid >> 6;
  const int m_off = (wv >> 1) << 6, n_off = (wv & 1) << 6;

  f32x4 acc[4][4] = {};
  for (int kb = 0; kb < ND / 32; ++kb) {
    const int k0 = kb * 32;
#pragma unroll
    for (int j = 0; j < 2; ++j) {
      int cid = j * 256 + tid;
      int row = cid >> 2, cc = cid & 3;
      int cs = cc ^ (row & 3);
      gload_lds16(A0 + (size_t)row * ND + k0 + cs * 8, (char*)lAx + cid * 16);
      gload_lds16(B0 + (size_t)row * ND + k0 + cs * 8, (char*)lBx + cid * 16);
    }
    __syncthreads();
    bf16x8 af[4], bfr[4];
#pragma unroll
    for (int i = 0; i < 4; ++i) {
      int row = m_off + i * 16 + (lane & 15);
      int ch = (lane >> 4) ^ (row & 3);
      af[i] = *(const bf16x8*)((const char*)lAx + row * 64 + ch * 16);
      int rowb = n_off + i * 16 + (lane & 15);
      int chb = (lane >> 4) ^ (rowb & 3);
      bfr[i] = *(const bf16x8*)((const char*)lBx + rowb * 64 + chb * 16);
    }
#pragma unroll
    for (int i = 0; i < 4; ++i)
#pragma unroll
      for (int j2 = 0; j2 < 4; ++j2)
        acc[i][j2] = __builtin_amdgcn_mfma_f32_16x16x32_bf16(af[i], bfr[j2], acc[i][j2], 0, 0, 0);
    __syncthreads();
  }
#pragma unroll
  for (int i = 0; i < 4; ++i)
#pragma unroll
    for (int j2 = 0; j2 < 4; ++j2)
#pragma unroll
      for (int r = 0; r < 4; ++r) {
        int m = m_off + i * 16 + ((lane >> 4) << 2) + r;
        int n = nb * 128 + n_off + j2 * 16 + (lane & 15);
        XP[((size_t)(m * NB + b)) * NG + n] = f2bf(acc[i][j2][r]);
      }
}

// ---------------- fused dispatch ----------------
// bids 0..127: LSTM (g_b 0..3 x g_d 0..31). bids 128..255: GEMM for chunk+1.
// 96KB dynamic LDS -> 1 WG/CU. h exchange uses slice-contiguous layout:
// hring[ring][group][32 slices][1KB]; producer slice == consumer LDS image.
// wave0 issues each slice's gload_lds as its producer's flag arrives
// (overlaps fetch with straggler tail), then vmcnt(0) + LDS release.
__global__ __launch_bounds__(512, 2) void k_fused(
    const uint16_t* __restrict__ embb,   // [64][1024][1024] bf16
    const uint16_t* __restrict__ Wx,
    const uint16_t* __restrict__ Wh,
    uint16_t* __restrict__ xpA, uint16_t* __restrict__ xpB,
    const float* __restrict__ b_i, const float* __restrict__ b_f,
    const float* __restrict__ b_g, const float* __restrict__ b_o,
    uint16_t* __restrict__ hring,        // [RING][4][32][512] u16 slices
    float* __restrict__ cbuf,
    uint32_t* __restrict__ flags,        // [NS][4][32] slots, 16B stride
    float* __restrict__ out, int chunk) {
  extern __shared__ char smem[];
  const int bid = blockIdx.x;
  const int tid = threadIdx.x;

  if (chunk < 0 || bid >= 128) {
    // ---------------- GEMM role: x_proj for chunk+1 ----------------
    const int gc = (chunk < 0) ? 0 : chunk + 1;
    if (gc >= NCHUNK) return;
    uint16_t* XP = (gc & 1) ? xpB : xpA;
    const int t0g = gc * CHUNK;
    const int t256 = tid & 255;
    char* lmem = smem + ((tid >> 8) << 14);
    if (chunk < 0) {
      // prologue: 512 workers, 2b x 2nb blocks
      int w = bid * 2 + (tid >> 8);
      int wb = w & 31, wn = w >> 5;
#pragma unroll
      for (int nbi = 0; nbi < 2; ++nbi)
#pragma unroll
        for (int bi = 0; bi < 2; ++bi) {
          int b = wb * 2 + bi, nb = wn * 2 + nbi;
          gemm_tile(embb + ((size_t)b * NS + t0g) * ND, Wx, XP, b, nb, t256, lmem);
        }
    } else {
      // steady: 256 workers, 4b x 2nb blocks (nb outer, b inner -> Wx L2 reuse)
      int w = (bid - 128) * 2 + (tid >> 8);
      int wb = w & 15, wn = w >> 4;
#pragma unroll
      for (int nbi = 0; nbi < 2; ++nbi)
#pragma unroll
        for (int bi = 0; bi < 4; ++bi) {
          int b = wb * 4 + bi, nb = wn * 2 + nbi;
          gemm_tile(embb + ((size_t)b * NS + t0g) * ND, Wx, XP, b, nb, t256, lmem);
        }
    }
    return;
  }

  // ---------------- LSTM role ----------------
  char* lbuf = smem;                              // 32 KB: 32 slices x 1KB
  int* prog = (int*)(smem + 32768);               // staged-step counter
  const int t0 = chunk * CHUNK;
  const uint16_t* XP = (chunk & 1) ? xpB : xpA;
  const char* hring_b = (const char*)hring;

  const int lane = tid & 63, wv = tid >> 6;
  const int xcd = bid & 7;
  const int g_b = xcd >> 1;
  const int g_d = (xcd & 1) + ((bid >> 3) << 1);  // 0..31

  const int q = lane >> 4, nl = lane & 15;
  const int g = nl & 3;                        // gate id (0=i,1=f,2=g,3=o)
  const int d_loc = wv * 4 + (nl >> 2);        // 0..31
  const int dg = g_d * 32 + d_loc;             // global d
  const int bg0 = g_b * 16 + q * 4;            // batch base for r=0..3
  const int aoff = (nl * 4 + q) * 16;          // A-fragment byte offset in slice

  const uint16_t* wrow = Wh + ((size_t)g * ND + dg) * ND;
  bf16x8 wfr[32];
#pragma unroll
  for (int kk = 0; kk < 32; ++kk)
    wfr[kk] = *(const bf16x8*)(wrow + kk * 32 + q * 8);

  const float* bptr = (g == 0) ? b_i : (g == 1) ? b_f : (g == 2) ? b_g : b_o;
  const float Bv = bptr[dg];

  float c0, c1, c2, c3;
  if (t0 == 0) {
    c0 = c1 = c2 = c3 = 0.f;
  } else {
    c0 = cbuf[(size_t)(bg0 + 0) * ND + dg];
    c1 = cbuf[(size_t)(bg0 + 1) * ND + dg];
    c2 = cbuf[(size_t)(bg0 + 2) * ND + dg];
    c3 = cbuf[(size_t)(bg0 + 3) * ND + dg];
  }

  if (tid == 0)
    __hip_atomic_store(prog, 0, __ATOMIC_RELAXED, __HIP_MEMORY_SCOPE_WORKGROUP);
  __syncthreads();

  // preload XP for t0
  const uint16_t* xp0 = XP + ((size_t)bg0) * NG + ((size_t)g << 10) + dg;
  uint16_t xc0 = xp0[0], xc1 = xp0[NG], xc2 = xp0[2 * (size_t)NG], xc3 = xp0[3 * (size_t)NG];

#pragma unroll 1
  for (int t = t0; t < t0 + CHUNK; ++t) {
    // prefetch next step's XP into regs (issued before the wait; covered by MFMA)
    int tn = t + 1 < t0 + CHUNK ? t + 1 : t;
    const uint16_t* xpn = XP + (((size_t)(tn - t0) * NB) + bg0) * NG + ((size_t)g << 10) + dg;
    uint16_t xn0 = xpn[0], xn1 = xpn[NG], xn2 = xpn[2 * (size_t)NG], xn3 = xpn[3 * (size_t)NG];

    f32x4 a0 = {0,0,0,0}, a1 = {0,0,0,0}, a2 = {0,0,0,0}, a3 = {0,0,0,0};
    if (t > 0) {
      const int sstep = (chunk == 0) ? (t - 1) : (t - t0);
      if (wv == 0) {
        // issue each slice's gload as its producer flag arrives
        const char* hb = hring_b + (size_t)((t - 1) & (RING - 1)) * 131072
                       + (size_t)g_b * 32768;
        const uint32_t* fl = flags + ((((size_t)(t - 1) * 4 + g_b) << 5) + (lane & 31)) * 4;
        uint64_t got = 0;
        while (got != 0xffffffffull) {
          uint32_t v = (lane < 32)
              ? __hip_atomic_load(fl, __ATOMIC_RELAXED, __HIP_MEMORY_SCOPE_AGENT) : 1u;
          uint64_t avail = (__ballot(v != 0) & 0xffffffffull) & ~got;
          while (avail) {
            int p = __builtin_ctzll(avail); avail &= avail - 1;
            gload_lds16_nc(hb + p * 1024 + lane * 16, lbuf + p * 1024 + lane * 16);
            got |= 1ull << p;
          }
        }
        WAITV0;   // all 32 slices in LDS
        __hip_atomic_store(prog, sstep + 1, __ATOMIC_RELAXED, __HIP_MEMORY_SCOPE_WORKGROUP);
      } else {
        while (__hip_atomic_load(prog, __ATOMIC_RELAXED, __HIP_MEMORY_SCOPE_WORKGROUP)
               < sstep + 1) {}
      }
#pragma unroll
      for (int kk = 0; kk < 32; ++kk) {
        bf16x8 af = *(const bf16x8*)(lbuf + kk * 1024 + aoff);
        if ((kk & 3) == 0)      a0 = __builtin_amdgcn_mfma_f32_16x16x32_bf16(af, wfr[kk], a0, 0, 0, 0);
        else if ((kk & 3) == 1) a1 = __builtin_amdgcn_mfma_f32_16x16x32_bf16(af, wfr[kk], a1, 0, 0, 0);
        else if ((kk & 3) == 2) a2 = __builtin_amdgcn_mfma_f32_16x16x32_bf16(af, wfr[kk], a2, 0, 0, 0);
        else                    a3 = __builtin_amdgcn_mfma_f32_16x16x32_bf16(af, wfr[kk], a3, 0, 0, 0);
      }
    }

    float xr[4] = { bf2f(xc0), bf2f(xc1), bf2f(xc2), bf2f(xc3) };
    float cc[4] = { c0, c1, c2, c3 };
    float hval = 0.f;
#pragma unroll
    for (int r = 0; r < 4; ++r) {
      float v = a0[r] + a1[r] + a2[r] + a3[r] + xr[r] + Bv;
      float act = (g == 2) ? tanhf_(v) : sigmoidf_(v);
      float s1 = __shfl_xor(act, 1);
      float pe = (g & 1) ? s1 : act;
      float po = (g & 1) ? act : s1;
      float qe = __shfl_xor(pe, 2);
      float qo = __shfl_xor(po, 2);
      float gi = (g & 2) ? qe : pe;
      float gf = (g & 2) ? qo : po;
      float gg2 = (g & 2) ? pe : qe;
      float go = (g & 2) ? po : qo;
      float cn = __builtin_fmaf(gf, cc[r], gi * gg2);
      cc[r] = cn;
      float h = go * tanhf_(cn);
      if (r == g) hval = h;
    }
    c0 = cc[0]; c1 = cc[1]; c2 = cc[2]; c3 = cc[3];

    // per-wave shuffle-pack -> slice-contiguous publish (8B agent stores)
    {
      int hv = (int)f2bf(hval);
      int p = __shfl_xor(hv, 4);
      uint32_t v32 = ((nl >> 2) & 1) ? ((uint32_t)p | ((uint32_t)hv << 16))
                                     : ((uint32_t)hv | ((uint32_t)p << 16));
      uint32_t hi = (uint32_t)__shfl_xor((int)v32, 8);
      if (nl < 4) {
        uint64_t val = (uint64_t)v32 | ((uint64_t)hi << 32);
        // slice g_d, lane position l = row*4 + chunk: row = q*4+nl, chunk = wv>>1, half = wv&1
        char* dst = (char*)hring + (size_t)(t & (RING - 1)) * 131072
                  + (size_t)g_b * 32768 + (size_t)g_d * 1024
                  + ((q * 4 + nl) * 4 + (wv >> 1)) * 16 + (wv & 1) * 8;
        __hip_atomic_store((uint64_t*)dst, val, __ATOMIC_RELAXED, __HIP_MEMORY_SCOPE_AGENT);
      }
    }
    if (t == NS - 1) out[(size_t)(bg0 + g) * ND + dg] = hval;

    __syncthreads();   // drains all waves' h stores; end-of-step (R9-verified)
    if (tid == 0)
      __hip_atomic_store(flags + ((((size_t)t * 4 + g_b) << 5) + g_d) * 4, 1u,
                         __ATOMIC_RELAXED, __HIP_MEMORY_SCOPE_AGENT);

    xc0 = xn0; xc1 = xn1; xc2 = xn2; xc3 = xn3;
  }

  float cstore = (g == 0) ? c0 : (g == 1) ? c1 : (g == 2) ? c2 : c3;
  cbuf[(size_t)(bg0 + g) * ND + dg] = cstore;
}

// ---------------- launch ----------------
extern "C" void kernel_launch(void* const* d_in, const int* in_sizes, int n_in,
                              void* d_out, int out_size, void* d_ws, size_t ws_size,
                              hipStream_t stream) {
  const float* emb = (const float*)d_in[0];
  const float* W_ii = (const float*)d_in[1];
  const float* b_ii = (const float*)d_in[2];
  const float* W_if = (const float*)d_in[3];
  const float* b_if = (const float*)d_in[4];
  const float* W_ig = (const float*)d_in[5];
  const float* b_ig = (const float*)d_in[6];
  const float* W_io = (const float*)d_in[7];
  const float* b_io = (const float*)d_in[8];
  const float* W_hi = (const float*)d_in[9];
  const float* W_hf = (const float*)d_in[10];
  const float* W_hg = (const float*)d_in[11];
  const float* W_ho = (const float*)d_in[12];

  char* ws = (char*)d_ws;
  uint16_t* embb  = (uint16_t*)ws;                       // 134217728 B [B][S][D] bf16
  uint16_t* wx    = (uint16_t*)(ws + 134217728);         // 8388608 B
  uint16_t* wh    = (uint16_t*)(ws + 142606336);         // 8388608 B
  uint16_t* xpA   = (uint16_t*)(ws + 150994944);         // 67108864 B
  uint16_t* xpB   = (uint16_t*)(ws + 218103808);         // 67108864 B
  uint16_t* hring = (uint16_t*)(ws + 285212672);         // 4194304 B [RING][4][32][512]
  float*    cbuf  = (float*)(ws + 289406976);            // 262144 B
  uint32_t* flags = (uint32_t*)(ws + 289669120);         // 2097152 B [NS][4][32] x16B

  hipMemsetAsync(flags, 0, 2097152, stream);

  k_cvt<<<2048, 256, 0, stream>>>(emb, embb, 64 * 1024 * 1024 / 4);
  k_cvt<<<256, 256, 0, stream>>>(W_ii, wx + 0 * 1048576, 262144);
  k_cvt<<<256, 256, 0, stream>>>(W_if, wx + 1 * 1048576, 262144);
  k_cvt<<<256, 256, 0, stream>>>(W_ig, wx + 2 * 1048576, 262144);
  k_cvt<<<256, 256, 0, stream>>>(W_io, wx + 3 * 1048576, 262144);
  k_cvt<<<256, 256, 0, stream>>>(W_hi, wh + 0 * 1048576, 262144);
  k_cvt<<<256, 256, 0, stream>>>(W_hf, wh + 1 * 1048576, 262144);
  k_cvt<<<256, 256, 0, stream>>>(W_hg, wh + 2 * 1048576, 262144);
  k_cvt<<<256, 256, 0, stream>>>(W_ho, wh + 3 * 1048576, 262144);

  const int SHM = 98304;   // 96 KB -> 1 WG/CU (R9's verified win)
  hipFuncSetAttribute((const void*)k_fused, hipFuncAttributeMaxDynamicSharedMemorySize, SHM);

  // prologue: all 256 WGs compute x_proj for chunk 0
  k_fused<<<256, 512, SHM, stream>>>(embb, wx, wh, xpA, xpB, b_ii, b_if, b_ig, b_io,
                                     hring, cbuf, flags, (float*)d_out, -1);
  for (int chk = 0; chk < NCHUNK; ++chk)
    k_fused<<<256, 512, SHM, stream>>>(embb, wx, wh, xpA, xpB, b_ii, b_if, b_ig, b_io,
                                       hring, cbuf, flags, (float*)d_out, chk);
}